// Round 1
// 78.280 us; speedup vs baseline: 1.0081x; 1.0081x over previous
//
#include <hip/hip_runtime.h>

#define BLOCK 256
#define PTS_PER_BLOCK 512          // 2 points per thread
#define NPTS (8 * 65536)

// One thread owns 2 consecutive points end-to-end (no half-split, no partial
// exchange, single barrier). All global IO is vectorized:
//   input : 3x dwordx2 per thread (8B aligned, 24B span)
//   eval  : 1x dwordx2
//   con   : 2x dwordx4
//   probs : 1x dwordx4
// Weights staged once in LDS as broadcasts: float4 {w0,w1,w2, b1+theta*w3},
// float2 {W2r0,W2r1}. theta is uniform per block (512 pts << 65536-pt batch).

__global__ __launch_bounds__(BLOCK, 4) void cubeflow_fused(
    const float* __restrict__ input,
    const float* __restrict__ latent,
    const float* __restrict__ W1,
    const float* __restrict__ b1,
    const float* __restrict__ W2,
    const float* __restrict__ b2,
    float* __restrict__ out)
{
    __shared__ float4 sW1[128];   // {w0,w1,w2, b1+theta*w3}
    __shared__ float2 sW2[128];   // {W2[0][h], W2[1][h]}

    const int t     = threadIdx.x;
    const int base  = blockIdx.x * PTS_PER_BLOCK;
    const int batch = base >> 16;                 // 128 blocks per batch
    const float theta = latent[batch] * 10.0f;    // uniform per block

    // ---- stage fused weights into LDS (threads 0..127) ----
    if (t < 128) {
        float4 w = *reinterpret_cast<const float4*>(W1 + 4 * t);
        w.w = fmaf(w.w, theta, b1[t]);            // fold b1 + theta*w3
        sW1[t] = w;
        sW2[t] = make_float2(W2[t], W2[128 + t]);
    }

    // ---- load this thread's 2 points: 3x float2 (8B aligned) ----
    const int p0 = base + 2 * t;
    const float2* ip = reinterpret_cast<const float2*>(input + 3 * p0);
    const float2 f0 = ip[0];
    const float2 f1 = ip[1];
    const float2 f2 = ip[2];
    const float x0a = f0.x, x1a = f0.y, x2a = f1.x;
    const float x0b = f1.y, x1b = f2.x, x2b = f2.y;

    float* __restrict__ out_eval  = out;             // NPTS
    float* __restrict__ out_con   = out + NPTS;      // NPTS*4
    float* __restrict__ out_probs = out + 5 * NPTS;  // NPTS*2

    // ---- eval + con (fp32, exact) ----
    {
        const float cth = cosf(theta);
        const float sth = sinf(theta);

        const float d0a = x0a - theta, d1a = x1a, d2a = x2a;
        const float d0b = x0b - theta, d1b = x1b, d2b = x2b;

        const float f1a = fmaf(1.4f * d0a, d0a, fmaf(1.4f * d1a, d1a, 0.2f * d2a * d2a)) - 0.5f;
        const float f1b = fmaf(1.4f * d0b, d0b, fmaf(1.4f * d1b, d1b, 0.2f * d2b * d2b)) - 0.5f;

        const float c2xa = fmaf(cth, d0a,  sth * d1a);
        const float c2ya = fmaf(cth, d1a, -sth * d0a);
        const float c2za = d2a + 0.4f;
        const float f2a = fmaf(3.8f * c2xa, c2xa, fmaf(0.6f * c2ya, c2ya, 3.8f * c2za * c2za)) - 0.5f;
        const float c2xb = fmaf(cth, d0b,  sth * d1b);
        const float c2yb = fmaf(cth, d1b, -sth * d0b);
        const float c2zb = d2b + 0.4f;
        const float f2b = fmaf(3.8f * c2xb, c2xb, fmaf(0.6f * c2yb, c2yb, 3.8f * c2zb * c2zb)) - 0.5f;

        const float c3xa = fmaf(cth, d0a, -sth * d1a);
        const float c3ya = fmaf(sth, d0a,  cth * d1a);
        const float c3za = d2a - 0.6f;
        const float f3a = fmaf(0.35f * c3xa, c3xa, fmaf(2.8f * c3ya, c3ya, 2.8f * c3za * c3za)) - 0.5f;
        const float c3xb = fmaf(cth, d0b, -sth * d1b);
        const float c3yb = fmaf(sth, d0b,  cth * d1b);
        const float c3zb = d2b - 0.6f;
        const float f3b = fmaf(0.35f * c3xb, c3xb, fmaf(2.8f * c3yb, c3yb, 2.8f * c3zb * c3zb)) - 0.5f;

        *reinterpret_cast<float2*>(out_eval + p0) =
            make_float2(fminf(f1a, fminf(f2a, f3a)), fminf(f1b, fminf(f2b, f3b)));

        float4* cp = reinterpret_cast<float4*>(out_con + 4 * p0);
        cp[0] = make_float4(x0a, x1a, x2a, theta);
        cp[1] = make_float4(x0b, x1b, x2b, theta);
    }

    __syncthreads();   // weights staged

    // ---- MLP: 128 hidden units, 2 points, 4 independent acc chains ----
    float a0a = 0.0f, a1a = 0.0f, a0b = 0.0f, a1b = 0.0f;
#pragma unroll 8
    for (int h = 0; h < 128; ++h) {
        const float4 w  = sW1[h];   // LDS broadcast
        const float2 w2 = sW2[h];   // LDS broadcast
        float hva = fmaf(x0a, w.x, fmaf(x1a, w.y, fmaf(x2a, w.z, w.w)));
        float hvb = fmaf(x0b, w.x, fmaf(x1b, w.y, fmaf(x2b, w.z, w.w)));
        hva = fmaxf(hva, 0.0f);
        hvb = fmaxf(hvb, 0.0f);
        a0a = fmaf(hva, w2.x, a0a);
        a1a = fmaf(hva, w2.y, a1a);
        a0b = fmaf(hvb, w2.x, a0b);
        a1b = fmaf(hvb, w2.y, a1b);
    }

    const float B0 = b2[0];
    const float B1 = b2[1];
    *reinterpret_cast<float4*>(out_probs + 2 * p0) =
        make_float4(a0a + B0, a1a + B1, a0b + B0, a1b + B1);
}

extern "C" void kernel_launch(void* const* d_in, const int* in_sizes, int n_in,
                              void* d_out, int out_size, void* d_ws, size_t ws_size,
                              hipStream_t stream) {
    const float* input  = (const float*)d_in[0];
    const float* latent = (const float*)d_in[1];
    const float* W1     = (const float*)d_in[2];
    const float* b1     = (const float*)d_in[3];
    const float* W2     = (const float*)d_in[4];
    const float* b2     = (const float*)d_in[5];
    float* out = (float*)d_out;

    const int nblocks = NPTS / PTS_PER_BLOCK;   // 1024
    hipLaunchKernelGGL(cubeflow_fused, dim3(nblocks), dim3(BLOCK), 0, stream,
                       input, latent, W1, b1, W2, b2, out);
}